// Round 1
// baseline (1006.132 us; speedup 1.0000x reference)
//
#include <hip/hip_runtime.h>
#include <hip/hip_bf16.h>
#include <stdint.h>

// ---------------------------------------------------------------------------
// Fused LoRA attention forward, MI355X (gfx950).
// Stages:
//   1. prep_w  x4 : W_eff[n][k] bf16 (transposed, K-contiguous) = base + 2*(a1@b1 + a2@b2)
//   2. cast_x     : x fp32 -> bf16 row-major [4096][2048]
//   3. gemm<0>    : X @ [Wq|Wk|Wv]_eff -> RoPE epilogue -> Q,K [B,H,S,128] bf16, V^T [B,H,128,S] bf16
//   4. flash_attn : causal online-softmax flash attention -> O [B,S,2048] bf16
//   5. gemm<1>    : O @ Wo^T -> fp32 d_out
// GEMM: 128x128 tile, BK=64, 4 waves (2x2 of 64x64), mfma_f32_16x16x32_bf16,
//       global_load_lds(16B) with source-pre-swizzled XOR LDS (2-way conflicts, free).
// ---------------------------------------------------------------------------

typedef __attribute__((ext_vector_type(8))) short    bf16x8;
typedef __attribute__((ext_vector_type(4))) float    f32x4;
typedef __attribute__((ext_vector_type(8))) unsigned short u16x8;
typedef __attribute__((ext_vector_type(4))) unsigned short u16x4;
typedef unsigned short u16;

#define DEVI static __device__ __forceinline__

constexpr int BATCH = 2, SEQ = 2048, DIM = 2048, HEADS = 16, HD = 128, RANK = 8;
constexpr int NTOK = BATCH * SEQ;   // 4096
constexpr int NQKV = 3 * DIM;       // 6144
constexpr float LORA_SC = 2.0f;

DEVI u16 f2bf(float f) {            // RNE fp32 -> bf16 (finite inputs)
  uint32_t u = __float_as_uint(f);
  return (u16)((u + 0x7FFFu + ((u >> 16) & 1u)) >> 16);
}

DEVI void gload_lds16(const u16* g, u16* l) {
  __builtin_amdgcn_global_load_lds((const __attribute__((address_space(1))) void*)g,
                                   (__attribute__((address_space(3))) void*)l, 16, 0, 0);
}

// ---- 1. weight prep: outT[n][k] = base[k][n] + 2*(sum_r a1[k][r]*b1[r][n&b1mask] + a2[k][r]*b2[r][n])
__global__ __launch_bounds__(256) void prep_w(
    const float* __restrict__ base, const float* __restrict__ a1,
    const float* __restrict__ b1, int b1mask,
    const float* __restrict__ a2, const float* __restrict__ b2,
    u16* __restrict__ outT) {
  __shared__ float tile[64 * 67];   // 67: 2-way bank (free) on transposed read
  const int t = threadIdx.x;
  const int n0 = blockIdx.x * 64, k0 = blockIdx.y * 64;
#pragma unroll
  for (int i = 0; i < 16; ++i) {    // coalesced read of 64(k) x 64(n)
    int e = i * 256 + t;
    int kl = e >> 6, nl = e & 63;
    tile[kl * 67 + nl] = base[(size_t)(k0 + kl) * DIM + n0 + nl];
  }
  __syncthreads();
#pragma unroll
  for (int i = 0; i < 16; ++i) {    // coalesced write of 64(n) x 64(k)
    int e = i * 256 + t;
    int nl = e >> 6, kl = e & 63;
    int n = n0 + nl, k = k0 + kl;
    float v = tile[kl * 67 + nl];
    if (a1 != nullptr) {
      float l1 = 0.f, l2 = 0.f;
#pragma unroll
      for (int r = 0; r < RANK; ++r) {
        l1 += a1[k * RANK + r] * b1[r * (b1mask + 1) + (n & b1mask)];
        l2 += a2[k * RANK + r] * b2[r * DIM + n];
      }
      v += LORA_SC * (l1 + l2);
    }
    outT[(size_t)n * DIM + k] = f2bf(v);
  }
}

// ---- 2. fp32 -> bf16 cast (vectorized)
__global__ __launch_bounds__(256) void cast_x(const float* __restrict__ x,
                                              u16* __restrict__ xb, int n8) {
  int i = blockIdx.x * 256 + threadIdx.x;
  if (i >= n8) return;
  const float4* p = (const float4*)x;
  float4 v0 = p[i * 2], v1 = p[i * 2 + 1];
  u16x8 o;
  o[0] = f2bf(v0.x); o[1] = f2bf(v0.y); o[2] = f2bf(v0.z); o[3] = f2bf(v0.w);
  o[4] = f2bf(v1.x); o[5] = f2bf(v1.y); o[6] = f2bf(v1.z); o[7] = f2bf(v1.w);
  *(u16x8*)(xb + (size_t)i * 8) = o;
}

// ---- 3/5. bf16 GEMM, A[M][K] @ Bt[N][K]^T. EPI=0: QKV+RoPE epilogue; EPI=1: fp32 store
template <int EPI>
__global__ __launch_bounds__(256, 2) void gemm_bf16(
    const u16* __restrict__ A, const u16* __restrict__ Bt,
    float* __restrict__ Cf, const float* __restrict__ freq,
    u16* __restrict__ Qo, u16* __restrict__ Ko, u16* __restrict__ Vo,
    int M, int N, int K, int nTN) {
  __shared__ u16 As[128 * 64];
  __shared__ u16 Bs[128 * 64];
  const int t = threadIdx.x;
  const int lane = t & 63, wid = t >> 6;
  const int wR = (wid >> 1) * 64, wC = (wid & 1) * 64;
  const int r15 = lane & 15, g = lane >> 4;
  const int nwg = gridDim.x, bid = blockIdx.x;
  const int wg = (bid & 7) * (nwg >> 3) + (bid >> 3);   // bijective XCD swizzle (nwg%8==0)
  const int tM = (wg / nTN) * 128, tN = (wg % nTN) * 128;

  f32x4 acc[4][4];
#pragma unroll
  for (int i = 0; i < 4; ++i)
#pragma unroll
    for (int j = 0; j < 4; ++j) acc[i][j] = f32x4{0.f, 0.f, 0.f, 0.f};

  const u16* Abase = A + (size_t)tM * K;
  const u16* Bbase = Bt + (size_t)tN * K;

  for (int k0 = 0; k0 < K; k0 += 64) {
    // stage A,B tiles (128x64 bf16 each). LDS linear dest; source pre-swizzled
    // so image is chunk^(row&7) 16B-XOR layout -> 2-way conflicts on ds_read_b128.
#pragma unroll
    for (int i = 0; i < 4; ++i) {
      int c = i * 256 + t, row = c >> 3, ch = c & 7;
      gload_lds16(Abase + (size_t)row * K + k0 + (ch ^ (row & 7)) * 8, &As[c * 8]);
    }
#pragma unroll
    for (int i = 0; i < 4; ++i) {
      int c = i * 256 + t, row = c >> 3, ch = c & 7;
      gload_lds16(Bbase + (size_t)row * K + k0 + (ch ^ (row & 7)) * 8, &Bs[c * 8]);
    }
    __syncthreads();
#pragma unroll
    for (int kk = 0; kk < 2; ++kk) {
      bf16x8 af[4], bf[4];
#pragma unroll
      for (int i = 0; i < 4; ++i) {
        int row = wR + i * 16 + r15;
        int ch = (kk * 4 + g) ^ (row & 7);
        af[i] = *(const bf16x8*)&As[row * 64 + ch * 8];
      }
#pragma unroll
      for (int j = 0; j < 4; ++j) {
        int row = wC + j * 16 + r15;
        int ch = (kk * 4 + g) ^ (row & 7);
        bf[j] = *(const bf16x8*)&Bs[row * 64 + ch * 8];
      }
#pragma unroll
      for (int i = 0; i < 4; ++i)
#pragma unroll
        for (int j = 0; j < 4; ++j)
          acc[i][j] = __builtin_amdgcn_mfma_f32_16x16x32_bf16(af[i], bf[j], acc[i][j], 0, 0, 0);
    }
    __syncthreads();
  }

  if (EPI == 0) {
    // one 128-wide head per block (tN % 128 == 0)
    const int proj = tN >> 11;          // 0=Q 1=K 2=V
    const int h = (tN & 2047) >> 7;
#pragma unroll
    for (int i = 0; i < 4; ++i) {
      int rbase = tM + wR + i * 16 + g * 4;   // 4-aligned token row
      int bb = rbase >> 11;
      int s4 = rbase & 2047;
#pragma unroll
      for (int j = 0; j < 4; ++j) {
        int d = wC + j * 16 + r15;            // 0..127 within head
        if (proj < 2) {
          u16* dst = (proj == 0) ? Qo : Ko;
#pragma unroll
          for (int r = 0; r < 4; ++r) {
            float v = acc[i][j][r];
            float o = __shfl_xor(v, 1);       // pair partner (d^1)
            int s = s4 + r;
            float2 cs = *(const float2*)&freq[s * 128 + (d >> 1) * 2];
            float out = (d & 1) ? fmaf(o, cs.y, v * cs.x)       // odd:  tr*sin + ti*cos
                                : fmaf(v, cs.x, -(o * cs.y));   // even: tr*cos - ti*sin
            dst[((size_t)(bb * HEADS + h) * SEQ + s) * HD + d] = f2bf(out);
          }
        } else {                              // V: store transposed [B,H,128,S]
          u16x4 pk;
          pk[0] = f2bf(acc[i][j][0]); pk[1] = f2bf(acc[i][j][1]);
          pk[2] = f2bf(acc[i][j][2]); pk[3] = f2bf(acc[i][j][3]);
          *(u16x4*)&Vo[((size_t)(bb * HEADS + h) * HD + d) * SEQ + s4] = pk;
        }
      }
    }
  } else {
#pragma unroll
    for (int i = 0; i < 4; ++i) {
      int row = tM + wR + i * 16 + g * 4;
#pragma unroll
      for (int j = 0; j < 4; ++j) {
        int col = tN + wC + j * 16 + r15;
#pragma unroll
        for (int r = 0; r < 4; ++r)
          Cf[(size_t)(row + r) * N + col] = acc[i][j][r];
      }
    }
  }
}

// ---- 4. causal flash attention. 4 waves x 16 q-rows, KV-block 64.
__global__ __launch_bounds__(256, 2) void flash_attn(
    const u16* __restrict__ Qb, const u16* __restrict__ Kb,
    const u16* __restrict__ Vt, u16* __restrict__ Ob) {
  __shared__ u16 Pl[4 * 1024];                // per-wave 16x64 bf16 P staging
  const int t = threadIdx.x, lane = t & 63, w = t >> 6;
  const int r15 = lane & 15, g = lane >> 4;
  const int qb = (int)gridDim.x - 1 - (int)blockIdx.x;  // heavy blocks first
  const int bh = blockIdx.y;
  const int r0 = qb * 64 + w * 16;
  const u16* Qh = Qb + (size_t)bh * SEQ * HD;
  const u16* Kh = Kb + (size_t)bh * SEQ * HD;
  const u16* Vh = Vt + (size_t)bh * HD * SEQ;
  u16* Pw = Pl + w * 1024;

  bf16x8 qf[4];                               // Q hoisted to registers
#pragma unroll
  for (int kq = 0; kq < 4; ++kq)
    qf[kq] = *(const bf16x8*)&Qh[(size_t)(r0 + r15) * HD + kq * 32 + g * 8];

  f32x4 o[8];
#pragma unroll
  for (int dt = 0; dt < 8; ++dt) o[dt] = f32x4{0.f, 0.f, 0.f, 0.f};
  float m[4], lsum[4];
#pragma unroll
  for (int r = 0; r < 4; ++r) { m[r] = -1e30f; lsum[r] = 0.f; }
  const float SCL = 0.08838834764831845f * 1.4426950408889634f;  // 1/sqrt(128)*log2e

  const int nkv = (qb + 1) * 64;
  for (int kb = 0; kb < nkv; kb += 64) {
    f32x4 sc[4];
#pragma unroll
    for (int tt = 0; tt < 4; ++tt) sc[tt] = f32x4{0.f, 0.f, 0.f, 0.f};
#pragma unroll
    for (int tt = 0; tt < 4; ++tt)
#pragma unroll
      for (int kq = 0; kq < 4; ++kq) {
        bf16x8 kf = *(const bf16x8*)&Kh[(size_t)(kb + tt * 16 + r15) * HD + kq * 32 + g * 8];
        sc[tt] = __builtin_amdgcn_mfma_f32_16x16x32_bf16(qf[kq], kf, sc[tt], 0, 0, 0);
      }
    const bool diag = (kb + 64 == nkv);
    float mloc[4];
#pragma unroll
    for (int r = 0; r < 4; ++r) mloc[r] = -1e30f;
#pragma unroll
    for (int tt = 0; tt < 4; ++tt)
#pragma unroll
      for (int r = 0; r < 4; ++r) {
        float v = sc[tt][r] * SCL;
        if (diag) {
          int col = kb + tt * 16 + r15;
          int row = r0 + g * 4 + r;
          if (col > row) v = -1e30f;
        }
        sc[tt][r] = v;
        mloc[r] = fmaxf(mloc[r], v);
      }
#pragma unroll
    for (int r = 0; r < 4; ++r) {
      mloc[r] = fmaxf(mloc[r], __shfl_xor(mloc[r], 1));
      mloc[r] = fmaxf(mloc[r], __shfl_xor(mloc[r], 2));
      mloc[r] = fmaxf(mloc[r], __shfl_xor(mloc[r], 4));
      mloc[r] = fmaxf(mloc[r], __shfl_xor(mloc[r], 8));
    }
    float al[4];
#pragma unroll
    for (int r = 0; r < 4; ++r) {
      float mn = fmaxf(m[r], mloc[r]);
      al[r] = exp2f(m[r] - mn);
      m[r] = mn;
    }
    float ps[4] = {0.f, 0.f, 0.f, 0.f};
#pragma unroll
    for (int tt = 0; tt < 4; ++tt)
#pragma unroll
      for (int r = 0; r < 4; ++r) {
        float p = exp2f(sc[tt][r] - m[r]);
        sc[tt][r] = p;
        ps[r] += p;
      }
#pragma unroll
    for (int r = 0; r < 4; ++r) lsum[r] = lsum[r] * al[r] + ps[r];
#pragma unroll
    for (int dt = 0; dt < 8; ++dt)
#pragma unroll
      for (int r = 0; r < 4; ++r) o[dt][r] *= al[r];

    // P: C-layout -> A-layout via per-wave LDS (XOR-swizzled rows, no barrier)
#pragma unroll
    for (int tt = 0; tt < 4; ++tt)
#pragma unroll
      for (int r = 0; r < 4; ++r) {
        int row = g * 4 + r;
        int byo = (row * 128 + (tt * 16 + r15) * 2) ^ ((row & 7) << 4);
        *(u16*)((char*)Pw + byo) = f2bf(sc[tt][r]);
      }
    bf16x8 pf[2];
#pragma unroll
    for (int kq = 0; kq < 2; ++kq) {
      int byo = (r15 * 128 + kq * 64 + g * 16) ^ ((r15 & 7) << 4);
      pf[kq] = *(const bf16x8*)((const char*)Pw + byo);
    }
#pragma unroll
    for (int dt = 0; dt < 8; ++dt)
#pragma unroll
      for (int kq = 0; kq < 2; ++kq) {
        bf16x8 vf = *(const bf16x8*)&Vh[(size_t)(dt * 16 + r15) * SEQ + kb + kq * 32 + g * 8];
        o[dt] = __builtin_amdgcn_mfma_f32_16x16x32_bf16(pf[kq], vf, o[dt], 0, 0, 0);
      }
  }
#pragma unroll
  for (int r = 0; r < 4; ++r) {
    lsum[r] += __shfl_xor(lsum[r], 1);
    lsum[r] += __shfl_xor(lsum[r], 2);
    lsum[r] += __shfl_xor(lsum[r], 4);
    lsum[r] += __shfl_xor(lsum[r], 8);
    lsum[r] = 1.0f / lsum[r];
  }
  const int b = bh >> 4, h = bh & 15;
#pragma unroll
  for (int dt = 0; dt < 8; ++dt)
#pragma unroll
    for (int r = 0; r < 4; ++r) {
      int s = r0 + g * 4 + r;
      Ob[(size_t)(b * SEQ + s) * DIM + h * HD + dt * 16 + r15] = f2bf(o[dt][r] * lsum[r]);
    }
}

// ---------------------------------------------------------------------------
extern "C" void kernel_launch(void* const* d_in, const int* in_sizes, int n_in,
                              void* d_out, int out_size, void* d_ws, size_t ws_size,
                              hipStream_t stream) {
  const float* x       = (const float*)d_in[0];
  const float* freq    = (const float*)d_in[1];
  const float* wq_base = (const float*)d_in[2];
  const float* wk_base = (const float*)d_in[3];
  const float* wv_base = (const float*)d_in[4];
  const float* head_a  = (const float*)d_in[5];
  const float* head_b  = (const float*)d_in[6];
  const float* q_a     = (const float*)d_in[7];
  const float* q_b     = (const float*)d_in[8];
  const float* k_a     = (const float*)d_in[9];
  const float* k_b     = (const float*)d_in[10];
  const float* v_a     = (const float*)d_in[11];
  const float* v_b     = (const float*)d_in[12];
  const float* wo      = (const float*)d_in[13];
  float* out = (float*)d_out;

  char* ws = (char*)d_ws;
  size_t off = 0;
  u16* Wcat = (u16*)(ws + off); off += (size_t)NQKV * DIM * 2;  // 25.2 MB, dead after gemm<0>
  u16* WoT  = (u16*)(ws + off); off += (size_t)DIM * DIM * 2;
  u16* Xb   = (u16*)(ws + off); off += (size_t)NTOK * DIM * 2;
  u16* Qb   = (u16*)(ws + off); off += (size_t)NTOK * DIM * 2;
  u16* Kb   = (u16*)(ws + off); off += (size_t)NTOK * DIM * 2;
  u16* Vt   = (u16*)(ws + off); off += (size_t)NTOK * DIM * 2;
  u16* Ob   = Wcat;                                            // alias (safe: Wcat dead)

  dim3 blk(256);
  dim3 gw(DIM / 64, DIM / 64);
  prep_w<<<gw, blk, 0, stream>>>(wq_base, q_a, q_b, HD - 1, head_a, head_b, Wcat);
  prep_w<<<gw, blk, 0, stream>>>(wk_base, k_a, k_b, HD - 1, head_a, head_b, Wcat + (size_t)DIM * DIM);
  prep_w<<<gw, blk, 0, stream>>>(wv_base, v_a, v_b, HD - 1, head_a, head_b, Wcat + (size_t)2 * DIM * DIM);
  prep_w<<<gw, blk, 0, stream>>>(wo, nullptr, nullptr, 0, nullptr, nullptr, WoT);
  cast_x<<<dim3(NTOK * DIM / 8 / 256), blk, 0, stream>>>(x, Xb, NTOK * DIM / 8);
  gemm_bf16<0><<<dim3((NTOK / 128) * (NQKV / 128)), blk, 0, stream>>>(
      Xb, Wcat, nullptr, freq, Qb, Kb, Vt, NTOK, NQKV, DIM, NQKV / 128);
  flash_attn<<<dim3(SEQ / 64, BATCH * HEADS), blk, 0, stream>>>(Qb, Kb, Vt, Ob);
  gemm_bf16<1><<<dim3((NTOK / 128) * (DIM / 128)), blk, 0, stream>>>(
      Ob, WoT, out, nullptr, nullptr, nullptr, nullptr, NTOK, DIM, DIM, DIM / 128);
}

// Round 7
// 532.837 us; speedup vs baseline: 1.8883x; 1.8883x over previous
//
#include <hip/hip_runtime.h>
#include <hip/hip_bf16.h>
#include <stdint.h>

// ---------------------------------------------------------------------------
// Fused LoRA attention forward, MI355X (gfx950).
// Stages:
//   1. prep_w  x4 : W_eff[n][k] bf16 (transposed, K-contiguous) = base + 2*(a1@b1 + a2@b2)
//   2. cast_x     : x fp32 -> bf16 row-major [4096][2048]
//   3. gemm<0>    : X @ [Wq|Wk|Wv]_eff -> RoPE epilogue -> Q,K [B,H,S,128] bf16, V^T [B,H,128,S] bf16
//   4. flash_attn : causal flash attention, 4 waves x 32 q-rows, KV in dbuf swizzled LDS
//   5. gemm<1>    : O @ Wo^T -> fp32 d_out
// ---------------------------------------------------------------------------

typedef __attribute__((ext_vector_type(8))) short    bf16x8;
typedef __attribute__((ext_vector_type(4))) float    f32x4;
typedef __attribute__((ext_vector_type(8))) unsigned short u16x8;
typedef __attribute__((ext_vector_type(4))) unsigned short u16x4;
typedef unsigned short u16;

#define DEVI static __device__ __forceinline__

constexpr int BATCH = 2, SEQ = 2048, DIM = 2048, HEADS = 16, HD = 128, RANK = 8;
constexpr int NTOK = BATCH * SEQ;   // 4096
constexpr int NQKV = 3 * DIM;       // 6144
constexpr float LORA_SC = 2.0f;

DEVI u16 f2bf(float f) {            // RNE fp32 -> bf16 (finite inputs)
  uint32_t u = __float_as_uint(f);
  return (u16)((u + 0x7FFFu + ((u >> 16) & 1u)) >> 16);
}

DEVI void gload_lds16(const u16* g, u16* l) {
  __builtin_amdgcn_global_load_lds((const __attribute__((address_space(1))) void*)g,
                                   (__attribute__((address_space(3))) void*)l, 16, 0, 0);
}

// ---- 1. weight prep: outT[n][k] = base[k][n] + 2*(sum_r a1[k][r]*b1[r][n&b1mask] + a2[k][r]*b2[r][n])
__global__ __launch_bounds__(256) void prep_w(
    const float* __restrict__ base, const float* __restrict__ a1,
    const float* __restrict__ b1, int b1mask,
    const float* __restrict__ a2, const float* __restrict__ b2,
    u16* __restrict__ outT) {
  __shared__ float tile[64 * 67];   // 67: 2-way bank (free) on transposed read
  const int t = threadIdx.x;
  const int n0 = blockIdx.x * 64, k0 = blockIdx.y * 64;
#pragma unroll
  for (int i = 0; i < 16; ++i) {    // coalesced read of 64(k) x 64(n)
    int e = i * 256 + t;
    int kl = e >> 6, nl = e & 63;
    tile[kl * 67 + nl] = base[(size_t)(k0 + kl) * DIM + n0 + nl];
  }
  __syncthreads();
#pragma unroll
  for (int i = 0; i < 16; ++i) {    // coalesced write of 64(n) x 64(k)
    int e = i * 256 + t;
    int nl = e >> 6, kl = e & 63;
    int n = n0 + nl, k = k0 + kl;
    float v = tile[kl * 67 + nl];
    if (a1 != nullptr) {
      float l1 = 0.f, l2 = 0.f;
#pragma unroll
      for (int r = 0; r < RANK; ++r) {
        l1 += a1[k * RANK + r] * b1[r * (b1mask + 1) + (n & b1mask)];
        l2 += a2[k * RANK + r] * b2[r * DIM + n];
      }
      v += LORA_SC * (l1 + l2);
    }
    outT[(size_t)n * DIM + k] = f2bf(v);
  }
}

// ---- 2. fp32 -> bf16 cast (vectorized)
__global__ __launch_bounds__(256) void cast_x(const float* __restrict__ x,
                                              u16* __restrict__ xb, int n8) {
  int i = blockIdx.x * 256 + threadIdx.x;
  if (i >= n8) return;
  const float4* p = (const float4*)x;
  float4 v0 = p[i * 2], v1 = p[i * 2 + 1];
  u16x8 o;
  o[0] = f2bf(v0.x); o[1] = f2bf(v0.y); o[2] = f2bf(v0.z); o[3] = f2bf(v0.w);
  o[4] = f2bf(v1.x); o[5] = f2bf(v1.y); o[6] = f2bf(v1.z); o[7] = f2bf(v1.w);
  *(u16x8*)(xb + (size_t)i * 8) = o;
}

// ---- 3/5. bf16 GEMM, A[M][K] @ Bt[N][K]^T. EPI=0: QKV+RoPE epilogue; EPI=1: fp32 store
template <int EPI>
__global__ __launch_bounds__(256, 2) void gemm_bf16(
    const u16* __restrict__ A, const u16* __restrict__ Bt,
    float* __restrict__ Cf, const float* __restrict__ freq,
    u16* __restrict__ Qo, u16* __restrict__ Ko, u16* __restrict__ Vo,
    int M, int N, int K, int nTN) {
  __shared__ u16 As[128 * 64];
  __shared__ u16 Bs[128 * 64];
  const int t = threadIdx.x;
  const int lane = t & 63, wid = t >> 6;
  const int wR = (wid >> 1) * 64, wC = (wid & 1) * 64;
  const int r15 = lane & 15, g = lane >> 4;
  const int nwg = gridDim.x, bid = blockIdx.x;
  const int wg = (bid & 7) * (nwg >> 3) + (bid >> 3);   // bijective XCD swizzle (nwg%8==0)
  const int tM = (wg / nTN) * 128, tN = (wg % nTN) * 128;

  f32x4 acc[4][4];
#pragma unroll
  for (int i = 0; i < 4; ++i)
#pragma unroll
    for (int j = 0; j < 4; ++j) acc[i][j] = f32x4{0.f, 0.f, 0.f, 0.f};

  const u16* Abase = A + (size_t)tM * K;
  const u16* Bbase = Bt + (size_t)tN * K;

  for (int k0 = 0; k0 < K; k0 += 64) {
    // stage A,B tiles (128x64 bf16 each). LDS linear dest; source pre-swizzled
    // so image is chunk^(row&7) 16B-XOR layout -> reduced conflicts on ds_read_b128.
#pragma unroll
    for (int i = 0; i < 4; ++i) {
      int c = i * 256 + t, row = c >> 3, ch = c & 7;
      gload_lds16(Abase + (size_t)row * K + k0 + (ch ^ (row & 7)) * 8, &As[c * 8]);
    }
#pragma unroll
    for (int i = 0; i < 4; ++i) {
      int c = i * 256 + t, row = c >> 3, ch = c & 7;
      gload_lds16(Bbase + (size_t)row * K + k0 + (ch ^ (row & 7)) * 8, &Bs[c * 8]);
    }
    __syncthreads();
#pragma unroll
    for (int kk = 0; kk < 2; ++kk) {
      bf16x8 af[4], bf[4];
#pragma unroll
      for (int i = 0; i < 4; ++i) {
        int row = wR + i * 16 + r15;
        int ch = (kk * 4 + g) ^ (row & 7);
        af[i] = *(const bf16x8*)&As[row * 64 + ch * 8];
      }
#pragma unroll
      for (int j = 0; j < 4; ++j) {
        int row = wC + j * 16 + r15;
        int ch = (kk * 4 + g) ^ (row & 7);
        bf[j] = *(const bf16x8*)&Bs[row * 64 + ch * 8];
      }
#pragma unroll
      for (int i = 0; i < 4; ++i)
#pragma unroll
        for (int j = 0; j < 4; ++j)
          acc[i][j] = __builtin_amdgcn_mfma_f32_16x16x32_bf16(af[i], bf[j], acc[i][j], 0, 0, 0);
    }
    __syncthreads();
  }

  if (EPI == 0) {
    // one 128-wide head per block (tN % 128 == 0)
    const int proj = tN >> 11;          // 0=Q 1=K 2=V
    const int h = (tN & 2047) >> 7;
#pragma unroll
    for (int i = 0; i < 4; ++i) {
      int rbase = tM + wR + i * 16 + g * 4;   // 4-aligned token row
      int bb = rbase >> 11;
      int s4 = rbase & 2047;
#pragma unroll
      for (int j = 0; j < 4; ++j) {
        int d = wC + j * 16 + r15;            // 0..127 within head
        if (proj < 2) {
          u16* dst = (proj == 0) ? Qo : Ko;
#pragma unroll
          for (int r = 0; r < 4; ++r) {
            float v = acc[i][j][r];
            float o = __shfl_xor(v, 1);       // pair partner (d^1)
            int s = s4 + r;
            float2 cs = *(const float2*)&freq[s * 128 + (d >> 1) * 2];
            float out = (d & 1) ? fmaf(o, cs.y, v * cs.x)       // odd:  tr*sin + ti*cos
                                : fmaf(v, cs.x, -(o * cs.y));   // even: tr*cos - ti*sin
            dst[((size_t)(bb * HEADS + h) * SEQ + s) * HD + d] = f2bf(out);
          }
        } else {                              // V: store transposed [B,H,128,S]
          u16x4 pk;
          pk[0] = f2bf(acc[i][j][0]); pk[1] = f2bf(acc[i][j][1]);
          pk[2] = f2bf(acc[i][j][2]); pk[3] = f2bf(acc[i][j][3]);
          *(u16x4*)&Vo[((size_t)(bb * HEADS + h) * HD + d) * SEQ + s4] = pk;
        }
      }
    }
  } else {
#pragma unroll
    for (int i = 0; i < 4; ++i) {
      int row = tM + wR + i * 16 + g * 4;
#pragma unroll
      for (int j = 0; j < 4; ++j) {
        int col = tN + wC + j * 16 + r15;
#pragma unroll
        for (int r = 0; r < 4; ++r)
          Cf[(size_t)(row + r) * N + col] = acc[i][j][r];
      }
    }
  }
}

// ---- 4. causal flash attention v2.
// Block = 4 waves; wave w owns 32 q-rows (two 16-row m-tiles) of a 128-row q-block.
// K (64x128) and V^T (128x64) staged in double-buffered XOR-swizzled LDS via
// global_load_lds(16B) with pre-swizzled source; 2-phase pipeline (stage t+1
// issued before compute on t, drained by the end-of-iter __syncthreads).
__global__ __launch_bounds__(256, 2) void flash_attn(
    const u16* __restrict__ Qb, const u16* __restrict__ Kb,
    const u16* __restrict__ Vt, u16* __restrict__ Ob) {
  __shared__ u16 Ks[2][64 * 128];   // [kv][d], rows 256B, chunk^=(row&7)
  __shared__ u16 Vs[2][128 * 64];   // [d][kv], rows 128B, chunk^=(row&7)
  __shared__ u16 Pl[4 * 2048];      // per-wave 2x (16x64) P staging
  const int t = threadIdx.x, lane = t & 63, w = t >> 6;
  const int r15 = lane & 15, g = lane >> 4;
  const int x = blockIdx.x;
  const int qb = (x & 1) ? (x >> 1) : ((int)gridDim.x - 1 - (x >> 1));  // zigzag: heavy/light pairs
  const int bh = blockIdx.y;
  const int Q0 = qb * 128;
  const int r0w = Q0 + w * 32;                // wave's first q-row
  const u16* Qh = Qb + (size_t)bh * SEQ * HD;
  const u16* Kh = Kb + (size_t)bh * SEQ * HD;
  const u16* Vh = Vt + (size_t)bh * HD * SEQ;
  u16* Pw = Pl + w * 2048;

  bf16x8 qf[2][4];                            // Q hoisted: 2 m-tiles x K=128
#pragma unroll
  for (int mi = 0; mi < 2; ++mi)
#pragma unroll
    for (int kq = 0; kq < 4; ++kq)
      qf[mi][kq] = *(const bf16x8*)&Qh[(size_t)(r0w + mi * 16 + r15) * HD + kq * 32 + g * 8];

  f32x4 o[2][8];
#pragma unroll
  for (int mi = 0; mi < 2; ++mi)
#pragma unroll
    for (int dt = 0; dt < 8; ++dt) o[mi][dt] = f32x4{0.f, 0.f, 0.f, 0.f};
  float mx[2][4], ls[2][4];
#pragma unroll
  for (int mi = 0; mi < 2; ++mi)
#pragma unroll
    for (int r = 0; r < 4; ++r) { mx[mi][r] = -1e30f; ls[mi][r] = 0.f; }
  const float SCL = 0.08838834764831845f * 1.4426950408889634f;  // 1/sqrt(128)*log2e

  auto stage = [&](int ti, int b) {
    int kb = ti * 64;
#pragma unroll
    for (int i = 0; i < 4; ++i) {             // K: 64 rows x 16 chunks
      int c = i * 256 + t, row = c >> 4, ch = c & 15;
      gload_lds16(&Kh[(size_t)(kb + row) * HD + ((ch ^ (row & 7)) * 8)], &Ks[b][c * 8]);
    }
#pragma unroll
    for (int i = 0; i < 4; ++i) {             // V^T: 128 rows x 8 chunks
      int c = i * 256 + t, row = c >> 3, ch = c & 7;
      gload_lds16(&Vh[(size_t)row * SEQ + kb + ((ch ^ (row & 7)) * 8)], &Vs[b][c * 8]);
    }
  };

  const int nt = 2 * qb + 2;                  // KV tiles of 64 covering [0, Q0+128)
  stage(0, 0);
  __syncthreads();
  int buf = 0;
  for (int ti = 0; ti < nt; ++ti) {
    const int kb = ti * 64;
    if (ti + 1 < nt) stage(ti + 1, buf ^ 1);  // prefetch overlaps compute
    if (kb <= r0w + 31) {                     // wave has live rows in this tile
      // ---- QK^T: K-fragments shared across both m-tiles
      f32x4 sc[2][4];
#pragma unroll
      for (int mi = 0; mi < 2; ++mi)
#pragma unroll
        for (int tt = 0; tt < 4; ++tt) sc[mi][tt] = f32x4{0.f, 0.f, 0.f, 0.f};
#pragma unroll
      for (int tt = 0; tt < 4; ++tt)
#pragma unroll
        for (int kq = 0; kq < 4; ++kq) {
          int row = tt * 16 + r15;
          int ch = (kq * 4 + g) ^ (row & 7);
          bf16x8 kf = *(const bf16x8*)&Ks[buf][row * 128 + ch * 8];
#pragma unroll
          for (int mi = 0; mi < 2; ++mi)
            sc[mi][tt] = __builtin_amdgcn_mfma_f32_16x16x32_bf16(qf[mi][kq], kf, sc[mi][tt], 0, 0, 0);
        }
      // ---- online softmax per m-tile
#pragma unroll
      for (int mi = 0; mi < 2; ++mi) {
        const int rbase = r0w + mi * 16;
        const bool dg = (kb + 63 > rbase);
        float mloc[4] = {-1e30f, -1e30f, -1e30f, -1e30f};
#pragma unroll
        for (int tt = 0; tt < 4; ++tt)
#pragma unroll
          for (int r = 0; r < 4; ++r) {
            float v = sc[mi][tt][r] * SCL;
            if (dg) {
              int col = kb + tt * 16 + r15;
              int row = rbase + g * 4 + r;
              if (col > row) v = -1e30f;
            }
            sc[mi][tt][r] = v;
            mloc[r] = fmaxf(mloc[r], v);
          }
#pragma unroll
        for (int r = 0; r < 4; ++r) {
          mloc[r] = fmaxf(mloc[r], __shfl_xor(mloc[r], 1));
          mloc[r] = fmaxf(mloc[r], __shfl_xor(mloc[r], 2));
          mloc[r] = fmaxf(mloc[r], __shfl_xor(mloc[r], 4));
          mloc[r] = fmaxf(mloc[r], __shfl_xor(mloc[r], 8));
        }
        float al[4];
#pragma unroll
        for (int r = 0; r < 4; ++r) {
          float mn = fmaxf(mx[mi][r], mloc[r]);
          al[r] = exp2f(mx[mi][r] - mn);
          mx[mi][r] = mn;
        }
        float ps[4] = {0.f, 0.f, 0.f, 0.f};
#pragma unroll
        for (int tt = 0; tt < 4; ++tt)
#pragma unroll
          for (int r = 0; r < 4; ++r) {
            float p = exp2f(sc[mi][tt][r] - mx[mi][r]);
            ps[r] += p;
            int row = g * 4 + r;
            int byo = (row * 128 + (tt * 16 + r15) * 2) ^ ((row & 7) << 4);
            *(u16*)((char*)(Pw + mi * 1024) + byo) = f2bf(p);
          }
#pragma unroll
        for (int r = 0; r < 4; ++r) ls[mi][r] = ls[mi][r] * al[r] + ps[r];
#pragma unroll
        for (int dt = 0; dt < 8; ++dt)
#pragma unroll
          for (int r = 0; r < 4; ++r) o[mi][dt][r] *= al[r];
      }
      // ---- PV: V-fragments shared across both m-tiles
      bf16x8 pf[2][2];
#pragma unroll
      for (int mi = 0; mi < 2; ++mi)
#pragma unroll
        for (int kq = 0; kq < 2; ++kq) {
          int byo = (r15 * 128 + kq * 64 + g * 16) ^ ((r15 & 7) << 4);
          pf[mi][kq] = *(const bf16x8*)((const char*)(Pw + mi * 1024) + byo);
        }
#pragma unroll
      for (int dt = 0; dt < 8; ++dt)
#pragma unroll
        for (int kq = 0; kq < 2; ++kq) {
          int row = dt * 16 + r15;
          int ch = (kq * 4 + g) ^ (row & 7);
          bf16x8 vf = *(const bf16x8*)&Vs[buf][row * 64 + ch * 8];
#pragma unroll
          for (int mi = 0; mi < 2; ++mi)
            o[mi][dt] = __builtin_amdgcn_mfma_f32_16x16x32_bf16(pf[mi][kq], vf, o[mi][dt], 0, 0, 0);
        }
    }
    __syncthreads();                          // drains stage vmcnt; protects dbuf swap
    buf ^= 1;
  }

  const int b = bh >> 4, h = bh & 15;
#pragma unroll
  for (int mi = 0; mi < 2; ++mi) {
#pragma unroll
    for (int r = 0; r < 4; ++r) {
      ls[mi][r] += __shfl_xor(ls[mi][r], 1);
      ls[mi][r] += __shfl_xor(ls[mi][r], 2);
      ls[mi][r] += __shfl_xor(ls[mi][r], 4);
      ls[mi][r] += __shfl_xor(ls[mi][r], 8);
      ls[mi][r] = 1.0f / ls[mi][r];
    }
#pragma unroll
    for (int dt = 0; dt < 8; ++dt)
#pragma unroll
      for (int r = 0; r < 4; ++r) {
        int s = r0w + mi * 16 + g * 4 + r;
        Ob[(size_t)(b * SEQ + s) * DIM + h * HD + dt * 16 + r15] = f2bf(o[mi][dt][r] * ls[mi][r]);
      }
  }
}

// ---------------------------------------------------------------------------
extern "C" void kernel_launch(void* const* d_in, const int* in_sizes, int n_in,
                              void* d_out, int out_size, void* d_ws, size_t ws_size,
                              hipStream_t stream) {
  const float* x       = (const float*)d_in[0];
  const float* freq    = (const float*)d_in[1];
  const float* wq_base = (const float*)d_in[2];
  const float* wk_base = (const float*)d_in[3];
  const float* wv_base = (const float*)d_in[4];
  const float* head_a  = (const float*)d_in[5];
  const float* head_b  = (const float*)d_in[6];
  const float* q_a     = (const float*)d_in[7];
  const float* q_b     = (const float*)d_in[8];
  const float* k_a     = (const float*)d_in[9];
  const float* k_b     = (const float*)d_in[10];
  const float* v_a     = (const float*)d_in[11];
  const float* v_b     = (const float*)d_in[12];
  const float* wo      = (const float*)d_in[13];
  float* out = (float*)d_out;

  char* ws = (char*)d_ws;
  size_t off = 0;
  u16* Wcat = (u16*)(ws + off); off += (size_t)NQKV * DIM * 2;  // 25.2 MB, dead after gemm<0>
  u16* WoT  = (u16*)(ws + off); off += (size_t)DIM * DIM * 2;
  u16* Xb   = (u16*)(ws + off); off += (size_t)NTOK * DIM * 2;
  u16* Qb   = (u16*)(ws + off); off += (size_t)NTOK * DIM * 2;
  u16* Kb   = (u16*)(ws + off); off += (size_t)NTOK * DIM * 2;
  u16* Vt   = (u16*)(ws + off); off += (size_t)NTOK * DIM * 2;
  u16* Ob   = Wcat;                                            // alias (safe: Wcat dead)

  dim3 blk(256);
  dim3 gw(DIM / 64, DIM / 64);
  prep_w<<<gw, blk, 0, stream>>>(wq_base, q_a, q_b, HD - 1, head_a, head_b, Wcat);
  prep_w<<<gw, blk, 0, stream>>>(wk_base, k_a, k_b, HD - 1, head_a, head_b, Wcat + (size_t)DIM * DIM);
  prep_w<<<gw, blk, 0, stream>>>(wv_base, v_a, v_b, HD - 1, head_a, head_b, Wcat + (size_t)2 * DIM * DIM);
  prep_w<<<gw, blk, 0, stream>>>(wo, nullptr, nullptr, 0, nullptr, nullptr, WoT);
  cast_x<<<dim3(NTOK * DIM / 8 / 256), blk, 0, stream>>>(x, Xb, NTOK * DIM / 8);
  gemm_bf16<0><<<dim3((NTOK / 128) * (NQKV / 128)), blk, 0, stream>>>(
      Xb, Wcat, nullptr, freq, Qb, Kb, Vt, NTOK, NQKV, DIM, NQKV / 128);
  flash_attn<<<dim3(SEQ / 128, BATCH * HEADS), blk, 0, stream>>>(Qb, Kb, Vt, Ob);
  gemm_bf16<1><<<dim3((NTOK / 128) * (DIM / 128)), blk, 0, stream>>>(
      Ob, WoT, out, nullptr, nullptr, nullptr, nullptr, NTOK, DIM, DIM, DIM / 128);
}

// Round 12
// 509.190 us; speedup vs baseline: 1.9759x; 1.0464x over previous
//
#include <hip/hip_runtime.h>
#include <hip/hip_bf16.h>
#include <stdint.h>

// ---------------------------------------------------------------------------
// Fused LoRA attention forward, MI355X (gfx950).
// Stages:
//   1. prep_w  x4 : W_eff[n][k] bf16 (transposed, K-contiguous) = base + 2*(a1@b1 + a2@b2)
//   2. cast_x     : x fp32 -> bf16 row-major [4096][2048]
//   3. gemm<0>    : X @ [Wq|Wk|Wv]_eff -> RoPE epilogue -> Q,K [B,H,S,128] bf16, V^T [B,H,128,S] bf16
//   4. flash_attn : causal flash attention, 4 waves x 32 q-rows, KV in dbuf swizzled LDS
//                   LDS = 72KB/block (was 80KB -> only 1 block/CU resident; 72KB -> 2 blocks/CU)
//   5. gemm<1>    : O @ Wo^T -> fp32 d_out
// ---------------------------------------------------------------------------

typedef __attribute__((ext_vector_type(8))) short    bf16x8;
typedef __attribute__((ext_vector_type(4))) float    f32x4;
typedef __attribute__((ext_vector_type(8))) unsigned short u16x8;
typedef __attribute__((ext_vector_type(4))) unsigned short u16x4;
typedef unsigned short u16;

#define DEVI static __device__ __forceinline__

constexpr int BATCH = 2, SEQ = 2048, DIM = 2048, HEADS = 16, HD = 128, RANK = 8;
constexpr int NTOK = BATCH * SEQ;   // 4096
constexpr int NQKV = 3 * DIM;       // 6144
constexpr float LORA_SC = 2.0f;

DEVI u16 f2bf(float f) {            // RNE fp32 -> bf16 (finite inputs)
  uint32_t u = __float_as_uint(f);
  return (u16)((u + 0x7FFFu + ((u >> 16) & 1u)) >> 16);
}

DEVI void gload_lds16(const u16* g, u16* l) {
  __builtin_amdgcn_global_load_lds((const __attribute__((address_space(1))) void*)g,
                                   (__attribute__((address_space(3))) void*)l, 16, 0, 0);
}

// ---- 1. weight prep: outT[n][k] = base[k][n] + 2*(sum_r a1[k][r]*b1[r][n&b1mask] + a2[k][r]*b2[r][n])
__global__ __launch_bounds__(256) void prep_w(
    const float* __restrict__ base, const float* __restrict__ a1,
    const float* __restrict__ b1, int b1mask,
    const float* __restrict__ a2, const float* __restrict__ b2,
    u16* __restrict__ outT) {
  __shared__ float tile[64 * 67];   // 67: 2-way bank (free) on transposed read
  const int t = threadIdx.x;
  const int n0 = blockIdx.x * 64, k0 = blockIdx.y * 64;
#pragma unroll
  for (int i = 0; i < 16; ++i) {    // coalesced read of 64(k) x 64(n)
    int e = i * 256 + t;
    int kl = e >> 6, nl = e & 63;
    tile[kl * 67 + nl] = base[(size_t)(k0 + kl) * DIM + n0 + nl];
  }
  __syncthreads();
#pragma unroll
  for (int i = 0; i < 16; ++i) {    // coalesced write of 64(n) x 64(k)
    int e = i * 256 + t;
    int nl = e >> 6, kl = e & 63;
    int n = n0 + nl, k = k0 + kl;
    float v = tile[kl * 67 + nl];
    if (a1 != nullptr) {
      float l1 = 0.f, l2 = 0.f;
#pragma unroll
      for (int r = 0; r < RANK; ++r) {
        l1 += a1[k * RANK + r] * b1[r * (b1mask + 1) + (n & b1mask)];
        l2 += a2[k * RANK + r] * b2[r * DIM + n];
      }
      v += LORA_SC * (l1 + l2);
    }
    outT[(size_t)n * DIM + k] = f2bf(v);
  }
}

// ---- 2. fp32 -> bf16 cast (vectorized)
__global__ __launch_bounds__(256) void cast_x(const float* __restrict__ x,
                                              u16* __restrict__ xb, int n8) {
  int i = blockIdx.x * 256 + threadIdx.x;
  if (i >= n8) return;
  const float4* p = (const float4*)x;
  float4 v0 = p[i * 2], v1 = p[i * 2 + 1];
  u16x8 o;
  o[0] = f2bf(v0.x); o[1] = f2bf(v0.y); o[2] = f2bf(v0.z); o[3] = f2bf(v0.w);
  o[4] = f2bf(v1.x); o[5] = f2bf(v1.y); o[6] = f2bf(v1.z); o[7] = f2bf(v1.w);
  *(u16x8*)(xb + (size_t)i * 8) = o;
}

// ---- 3/5. bf16 GEMM, A[M][K] @ Bt[N][K]^T. EPI=0: QKV+RoPE epilogue; EPI=1: fp32 store
template <int EPI>
__global__ __launch_bounds__(256, 2) void gemm_bf16(
    const u16* __restrict__ A, const u16* __restrict__ Bt,
    float* __restrict__ Cf, const float* __restrict__ freq,
    u16* __restrict__ Qo, u16* __restrict__ Ko, u16* __restrict__ Vo,
    int M, int N, int K, int nTN) {
  __shared__ u16 As[128 * 64];
  __shared__ u16 Bs[128 * 64];
  const int t = threadIdx.x;
  const int lane = t & 63, wid = t >> 6;
  const int wR = (wid >> 1) * 64, wC = (wid & 1) * 64;
  const int r15 = lane & 15, g = lane >> 4;
  const int nwg = gridDim.x, bid = blockIdx.x;
  const int wg = (bid & 7) * (nwg >> 3) + (bid >> 3);   // bijective XCD swizzle (nwg%8==0)
  const int tM = (wg / nTN) * 128, tN = (wg % nTN) * 128;

  f32x4 acc[4][4];
#pragma unroll
  for (int i = 0; i < 4; ++i)
#pragma unroll
    for (int j = 0; j < 4; ++j) acc[i][j] = f32x4{0.f, 0.f, 0.f, 0.f};

  const u16* Abase = A + (size_t)tM * K;
  const u16* Bbase = Bt + (size_t)tN * K;

  for (int k0 = 0; k0 < K; k0 += 64) {
    // stage A,B tiles (128x64 bf16 each). LDS linear dest; source pre-swizzled
    // so image is chunk^(row&7) 16B-XOR layout -> reduced conflicts on ds_read_b128.
#pragma unroll
    for (int i = 0; i < 4; ++i) {
      int c = i * 256 + t, row = c >> 3, ch = c & 7;
      gload_lds16(Abase + (size_t)row * K + k0 + (ch ^ (row & 7)) * 8, &As[c * 8]);
    }
#pragma unroll
    for (int i = 0; i < 4; ++i) {
      int c = i * 256 + t, row = c >> 3, ch = c & 7;
      gload_lds16(Bbase + (size_t)row * K + k0 + (ch ^ (row & 7)) * 8, &Bs[c * 8]);
    }
    __syncthreads();
#pragma unroll
    for (int kk = 0; kk < 2; ++kk) {
      bf16x8 af[4], bf[4];
#pragma unroll
      for (int i = 0; i < 4; ++i) {
        int row = wR + i * 16 + r15;
        int ch = (kk * 4 + g) ^ (row & 7);
        af[i] = *(const bf16x8*)&As[row * 64 + ch * 8];
      }
#pragma unroll
      for (int j = 0; j < 4; ++j) {
        int row = wC + j * 16 + r15;
        int ch = (kk * 4 + g) ^ (row & 7);
        bf[j] = *(const bf16x8*)&Bs[row * 64 + ch * 8];
      }
#pragma unroll
      for (int i = 0; i < 4; ++i)
#pragma unroll
        for (int j = 0; j < 4; ++j)
          acc[i][j] = __builtin_amdgcn_mfma_f32_16x16x32_bf16(af[i], bf[j], acc[i][j], 0, 0, 0);
    }
    __syncthreads();
  }

  if (EPI == 0) {
    // one 128-wide head per block (tN % 128 == 0)
    const int proj = tN >> 11;          // 0=Q 1=K 2=V
    const int h = (tN & 2047) >> 7;
#pragma unroll
    for (int i = 0; i < 4; ++i) {
      int rbase = tM + wR + i * 16 + g * 4;   // 4-aligned token row
      int bb = rbase >> 11;
      int s4 = rbase & 2047;
#pragma unroll
      for (int j = 0; j < 4; ++j) {
        int d = wC + j * 16 + r15;            // 0..127 within head
        if (proj < 2) {
          u16* dst = (proj == 0) ? Qo : Ko;
#pragma unroll
          for (int r = 0; r < 4; ++r) {
            float v = acc[i][j][r];
            float o = __shfl_xor(v, 1);       // pair partner (d^1)
            int s = s4 + r;
            float2 cs = *(const float2*)&freq[s * 128 + (d >> 1) * 2];
            float out = (d & 1) ? fmaf(o, cs.y, v * cs.x)       // odd:  tr*sin + ti*cos
                                : fmaf(v, cs.x, -(o * cs.y));   // even: tr*cos - ti*sin
            dst[((size_t)(bb * HEADS + h) * SEQ + s) * HD + d] = f2bf(out);
          }
        } else {                              // V: store transposed [B,H,128,S]
          u16x4 pk;
          pk[0] = f2bf(acc[i][j][0]); pk[1] = f2bf(acc[i][j][1]);
          pk[2] = f2bf(acc[i][j][2]); pk[3] = f2bf(acc[i][j][3]);
          *(u16x4*)&Vo[((size_t)(bb * HEADS + h) * HD + d) * SEQ + s4] = pk;
        }
      }
    }
  } else {
#pragma unroll
    for (int i = 0; i < 4; ++i) {
      int row = tM + wR + i * 16 + g * 4;
#pragma unroll
      for (int j = 0; j < 4; ++j) {
        int col = tN + wC + j * 16 + r15;
#pragma unroll
        for (int r = 0; r < 4; ++r)
          Cf[(size_t)(row + r) * N + col] = acc[i][j][r];
      }
    }
  }
}

// ---- 4. causal flash attention v3.
// Block = 4 waves; wave w owns 32 q-rows (two 16-row m-tiles) of a 128-row q-block.
// K (64x128) and V^T (128x64) staged in double-buffered XOR-swizzled LDS via
// global_load_lds(16B) with pre-swizzled source; 2-phase pipeline.
// v3: P staging buffer reused across the two m-tiles (softmax->write->read per
// m-tile, sequentially) -> Pl 16KB->8KB -> LDS 72KB/block -> 2 blocks/CU.
__global__ __launch_bounds__(256, 2) void flash_attn(
    const u16* __restrict__ Qb, const u16* __restrict__ Kb,
    const u16* __restrict__ Vt, u16* __restrict__ Ob) {
  __shared__ u16 Ks[2][64 * 128];   // [kv][d], rows 256B, chunk^=(row&7)  (32KB)
  __shared__ u16 Vs[2][128 * 64];   // [d][kv], rows 128B, chunk^=(row&7)  (32KB)
  __shared__ u16 Pl[4 * 1024];      // per-wave 16x64 P staging, reused per m-tile (8KB)
  const int t = threadIdx.x, lane = t & 63, w = t >> 6;
  const int r15 = lane & 15, g = lane >> 4;
  const int x = blockIdx.x;
  const int qb = (x & 1) ? (x >> 1) : ((int)gridDim.x - 1 - (x >> 1));  // zigzag: heavy/light pairs
  const int bh = blockIdx.y;
  const int Q0 = qb * 128;
  const int r0w = Q0 + w * 32;                // wave's first q-row
  const u16* Qh = Qb + (size_t)bh * SEQ * HD;
  const u16* Kh = Kb + (size_t)bh * SEQ * HD;
  const u16* Vh = Vt + (size_t)bh * HD * SEQ;
  u16* Pw = Pl + w * 1024;

  bf16x8 qf[2][4];                            // Q hoisted: 2 m-tiles x K=128
#pragma unroll
  for (int mi = 0; mi < 2; ++mi)
#pragma unroll
    for (int kq = 0; kq < 4; ++kq)
      qf[mi][kq] = *(const bf16x8*)&Qh[(size_t)(r0w + mi * 16 + r15) * HD + kq * 32 + g * 8];

  f32x4 o[2][8];
#pragma unroll
  for (int mi = 0; mi < 2; ++mi)
#pragma unroll
    for (int dt = 0; dt < 8; ++dt) o[mi][dt] = f32x4{0.f, 0.f, 0.f, 0.f};
  float mx[2][4], ls[2][4];
#pragma unroll
  for (int mi = 0; mi < 2; ++mi)
#pragma unroll
    for (int r = 0; r < 4; ++r) { mx[mi][r] = -1e30f; ls[mi][r] = 0.f; }
  const float SCL = 0.08838834764831845f * 1.4426950408889634f;  // 1/sqrt(128)*log2e

  auto stage = [&](int ti, int b) {
    int kb = ti * 64;
#pragma unroll
    for (int i = 0; i < 4; ++i) {             // K: 64 rows x 16 chunks
      int c = i * 256 + t, row = c >> 4, ch = c & 15;
      gload_lds16(&Kh[(size_t)(kb + row) * HD + ((ch ^ (row & 7)) * 8)], &Ks[b][c * 8]);
    }
#pragma unroll
    for (int i = 0; i < 4; ++i) {             // V^T: 128 rows x 8 chunks
      int c = i * 256 + t, row = c >> 3, ch = c & 7;
      gload_lds16(&Vh[(size_t)row * SEQ + kb + ((ch ^ (row & 7)) * 8)], &Vs[b][c * 8]);
    }
  };

  const int nt = 2 * qb + 2;                  // KV tiles of 64 covering [0, Q0+128)
  stage(0, 0);
  __syncthreads();
  int buf = 0;
  for (int ti = 0; ti < nt; ++ti) {
    const int kb = ti * 64;
    if (ti + 1 < nt) stage(ti + 1, buf ^ 1);  // prefetch overlaps compute
    if (kb <= r0w + 31) {                     // wave has live rows in this tile
      // ---- QK^T: K-fragments shared across both m-tiles
      f32x4 sc[2][4];
#pragma unroll
      for (int mi = 0; mi < 2; ++mi)
#pragma unroll
        for (int tt = 0; tt < 4; ++tt) sc[mi][tt] = f32x4{0.f, 0.f, 0.f, 0.f};
#pragma unroll
      for (int tt = 0; tt < 4; ++tt)
#pragma unroll
        for (int kq = 0; kq < 4; ++kq) {
          int row = tt * 16 + r15;
          int ch = (kq * 4 + g) ^ (row & 7);
          bf16x8 kf = *(const bf16x8*)&Ks[buf][row * 128 + ch * 8];
#pragma unroll
          for (int mi = 0; mi < 2; ++mi)
            sc[mi][tt] = __builtin_amdgcn_mfma_f32_16x16x32_bf16(qf[mi][kq], kf, sc[mi][tt], 0, 0, 0);
        }
      // ---- per m-tile: online softmax -> P write -> P fragment read (Pw reused)
      bf16x8 pf[2][2];
#pragma unroll
      for (int mi = 0; mi < 2; ++mi) {
        const int rbase = r0w + mi * 16;
        const bool dg = (kb + 63 > rbase);
        float mloc[4] = {-1e30f, -1e30f, -1e30f, -1e30f};
#pragma unroll
        for (int tt = 0; tt < 4; ++tt)
#pragma unroll
          for (int r = 0; r < 4; ++r) {
            float v = sc[mi][tt][r] * SCL;
            if (dg) {
              int col = kb + tt * 16 + r15;
              int row = rbase + g * 4 + r;
              if (col > row) v = -1e30f;
            }
            sc[mi][tt][r] = v;
            mloc[r] = fmaxf(mloc[r], v);
          }
#pragma unroll
        for (int r = 0; r < 4; ++r) {
          mloc[r] = fmaxf(mloc[r], __shfl_xor(mloc[r], 1));
          mloc[r] = fmaxf(mloc[r], __shfl_xor(mloc[r], 2));
          mloc[r] = fmaxf(mloc[r], __shfl_xor(mloc[r], 4));
          mloc[r] = fmaxf(mloc[r], __shfl_xor(mloc[r], 8));
        }
        float al[4];
#pragma unroll
        for (int r = 0; r < 4; ++r) {
          float mn = fmaxf(mx[mi][r], mloc[r]);
          al[r] = exp2f(mx[mi][r] - mn);
          mx[mi][r] = mn;
        }
        float ps[4] = {0.f, 0.f, 0.f, 0.f};
#pragma unroll
        for (int tt = 0; tt < 4; ++tt)
#pragma unroll
          for (int r = 0; r < 4; ++r) {
            float p = exp2f(sc[mi][tt][r] - mx[mi][r]);
            ps[r] += p;
            int row = g * 4 + r;
            int byo = (row * 128 + (tt * 16 + r15) * 2) ^ ((row & 7) << 4);
            *(u16*)((char*)Pw + byo) = f2bf(p);
          }
#pragma unroll
        for (int r = 0; r < 4; ++r) ls[mi][r] = ls[mi][r] * al[r] + ps[r];
#pragma unroll
        for (int dt = 0; dt < 8; ++dt)
#pragma unroll
          for (int r = 0; r < 4; ++r) o[mi][dt][r] *= al[r];
        // read this m-tile's P fragments before Pw is overwritten by mi+1
        // (same-wave RAW through LDS; compiler inserts the lgkmcnt wait)
#pragma unroll
        for (int kq = 0; kq < 2; ++kq) {
          int byo = (r15 * 128 + kq * 64 + g * 16) ^ ((r15 & 7) << 4);
          pf[mi][kq] = *(const bf16x8*)((const char*)Pw + byo);
        }
      }
      // ---- PV: V-fragments shared across both m-tiles
#pragma unroll
      for (int dt = 0; dt < 8; ++dt)
#pragma unroll
        for (int kq = 0; kq < 2; ++kq) {
          int row = dt * 16 + r15;
          int ch = (kq * 4 + g) ^ (row & 7);
          bf16x8 vf = *(const bf16x8*)&Vs[buf][row * 64 + ch * 8];
#pragma unroll
          for (int mi = 0; mi < 2; ++mi)
            o[mi][dt] = __builtin_amdgcn_mfma_f32_16x16x32_bf16(pf[mi][kq], vf, o[mi][dt], 0, 0, 0);
        }
    }
    __syncthreads();                          // drains stage vmcnt; protects dbuf swap
    buf ^= 1;
  }

  const int b = bh >> 4, h = bh & 15;
#pragma unroll
  for (int mi = 0; mi < 2; ++mi) {
#pragma unroll
    for (int r = 0; r < 4; ++r) {
      ls[mi][r] += __shfl_xor(ls[mi][r], 1);
      ls[mi][r] += __shfl_xor(ls[mi][r], 2);
      ls[mi][r] += __shfl_xor(ls[mi][r], 4);
      ls[mi][r] += __shfl_xor(ls[mi][r], 8);
      ls[mi][r] = 1.0f / ls[mi][r];
    }
#pragma unroll
    for (int dt = 0; dt < 8; ++dt)
#pragma unroll
      for (int r = 0; r < 4; ++r) {
        int s = r0w + mi * 16 + g * 4 + r;
        Ob[(size_t)(b * SEQ + s) * DIM + h * HD + dt * 16 + r15] = f2bf(o[mi][dt][r] * ls[mi][r]);
      }
  }
}

// ---------------------------------------------------------------------------
extern "C" void kernel_launch(void* const* d_in, const int* in_sizes, int n_in,
                              void* d_out, int out_size, void* d_ws, size_t ws_size,
                              hipStream_t stream) {
  const float* x       = (const float*)d_in[0];
  const float* freq    = (const float*)d_in[1];
  const float* wq_base = (const float*)d_in[2];
  const float* wk_base = (const float*)d_in[3];
  const float* wv_base = (const float*)d_in[4];
  const float* head_a  = (const float*)d_in[5];
  const float* head_b  = (const float*)d_in[6];
  const float* q_a     = (const float*)d_in[7];
  const float* q_b     = (const float*)d_in[8];
  const float* k_a     = (const float*)d_in[9];
  const float* k_b     = (const float*)d_in[10];
  const float* v_a     = (const float*)d_in[11];
  const float* v_b     = (const float*)d_in[12];
  const float* wo      = (const float*)d_in[13];
  float* out = (float*)d_out;

  char* ws = (char*)d_ws;
  size_t off = 0;
  u16* Wcat = (u16*)(ws + off); off += (size_t)NQKV * DIM * 2;  // 25.2 MB, dead after gemm<0>
  u16* WoT  = (u16*)(ws + off); off += (size_t)DIM * DIM * 2;
  u16* Xb   = (u16*)(ws + off); off += (size_t)NTOK * DIM * 2;
  u16* Qb   = (u16*)(ws + off); off += (size_t)NTOK * DIM * 2;
  u16* Kb   = (u16*)(ws + off); off += (size_t)NTOK * DIM * 2;
  u16* Vt   = (u16*)(ws + off); off += (size_t)NTOK * DIM * 2;
  u16* Ob   = Wcat;                                            // alias (safe: Wcat dead)

  dim3 blk(256);
  dim3 gw(DIM / 64, DIM / 64);
  prep_w<<<gw, blk, 0, stream>>>(wq_base, q_a, q_b, HD - 1, head_a, head_b, Wcat);
  prep_w<<<gw, blk, 0, stream>>>(wk_base, k_a, k_b, HD - 1, head_a, head_b, Wcat + (size_t)DIM * DIM);
  prep_w<<<gw, blk, 0, stream>>>(wv_base, v_a, v_b, HD - 1, head_a, head_b, Wcat + (size_t)2 * DIM * DIM);
  prep_w<<<gw, blk, 0, stream>>>(wo, nullptr, nullptr, 0, nullptr, nullptr, WoT);
  cast_x<<<dim3(NTOK * DIM / 8 / 256), blk, 0, stream>>>(x, Xb, NTOK * DIM / 8);
  gemm_bf16<0><<<dim3((NTOK / 128) * (NQKV / 128)), blk, 0, stream>>>(
      Xb, Wcat, nullptr, freq, Qb, Kb, Vt, NTOK, NQKV, DIM, NQKV / 128);
  flash_attn<<<dim3(SEQ / 128, BATCH * HEADS), blk, 0, stream>>>(Qb, Kb, Vt, Ob);
  gemm_bf16<1><<<dim3((NTOK / 128) * (DIM / 128)), blk, 0, stream>>>(
      Ob, WoT, out, nullptr, nullptr, nullptr, nullptr, NTOK, DIM, DIM, DIM / 128);
}